// Round 2
// baseline (1002.937 us; speedup 1.0000x reference)
//
#include <hip/hip_runtime.h>
#include <math.h>

// LePE attention (CSWin vertical split), fp32 baseline.
// Shapes fixed by setup_inputs(): b=16, h=w=56, dim=256, heads=8, hd=32,
// h_sp=56, w_sp=7 -> 128 windows of S=392 tokens, 8 heads -> 1024 blocks.
//
// Scheme A: one block per (window, head), 256 threads, 2 query rows/thread.
// K+V staged in LDS (98 KiB -> 1 block/CU, 4 waves). Main-loop K/V reads are
// wave-uniform broadcasts (conflict-free). LePE written into dead K buffer
// with 16B-block XOR swizzle so the per-row float4 epilogue reads spread
// across banks.

#define BATCH 16
#define HH 56
#define WW 56
#define WSP 7
#define NWIN 8            // windows per image = 56/7
#define NHEAD 8
#define HD 32             // head dim
#define DIMC 256
#define NTOK (HH * WW)    // 3136
#define S 392             // tokens per window (56*7)
#define QSCALE 0.17677669529663687f  // 32^-0.5

__global__ __launch_bounds__(256, 1)
void lepe_attn_kernel(const float* __restrict__ qkv,
                      const float* __restrict__ conv_w,
                      const float* __restrict__ conv_b,
                      float* __restrict__ out)
{
    __shared__ float4 Ks4[S * 8];   // K tile; later reused as LePE output
    __shared__ float4 Vs4[S * 8];   // V tile
    float* Ks = (float*)Ks4;
    float* Vs = (float*)Vs4;

    const int tid  = threadIdx.x;
    const int bid  = blockIdx.x;
    const int head = bid & 7;
    const int gw   = bid >> 3;        // global window id
    const int b    = gw >> 3;         // batch
    const int wi   = gw & 7;          // window column index
    const int coff = head * HD;

    const float* qbase = qkv + (size_t)(0 * BATCH + b) * NTOK * DIMC;
    const float* kbase = qkv + (size_t)(1 * BATCH + b) * NTOK * DIMC;
    const float* vbase = qkv + (size_t)(2 * BATCH + b) * NTOK * DIMC;

    // ---- stage K, V into LDS (8 float4 per token row, coalesced 128B/token)
    for (int i = tid; i < S * 8; i += 256) {
        const int t   = i >> 3;
        const int seg = i & 7;
        const int n   = (t / WSP) * WW + wi * WSP + (t % WSP);
        const size_t g = (size_t)n * DIMC + coff + seg * 4;
        Ks4[i] = *(const float4*)(kbase + g);
        Vs4[i] = *(const float4*)(vbase + g);
    }

    // ---- per-thread query rows: r0 = tid, r1 = tid+256 (clamped if OOR)
    const int  r0 = tid;
    const bool w1 = (tid + 256 < S);
    const int  r1 = w1 ? (tid + 256) : (S - 1);

    float q0[HD], q1[HD], o0[HD], o1[HD];
    {
        const int n0 = (r0 / WSP) * WW + wi * WSP + (r0 % WSP);
        const int n1 = (r1 / WSP) * WW + wi * WSP + (r1 % WSP);
        const float4* p0 = (const float4*)(qbase + (size_t)n0 * DIMC + coff);
        const float4* p1 = (const float4*)(qbase + (size_t)n1 * DIMC + coff);
#pragma unroll
        for (int c = 0; c < 8; ++c) {
            const float4 a = p0[c];
            const float4 d = p1[c];
            q0[4*c+0] = a.x * QSCALE; q0[4*c+1] = a.y * QSCALE;
            q0[4*c+2] = a.z * QSCALE; q0[4*c+3] = a.w * QSCALE;
            q1[4*c+0] = d.x * QSCALE; q1[4*c+1] = d.y * QSCALE;
            q1[4*c+2] = d.z * QSCALE; q1[4*c+3] = d.w * QSCALE;
            o0[4*c+0] = 0.f; o0[4*c+1] = 0.f; o0[4*c+2] = 0.f; o0[4*c+3] = 0.f;
            o1[4*c+0] = 0.f; o1[4*c+1] = 0.f; o1[4*c+2] = 0.f; o1[4*c+3] = 0.f;
        }
    }

    float m0 = -INFINITY, m1 = -INFINITY, l0 = 0.f, l1 = 0.f;

    __syncthreads();

    // ---- online-softmax flash loop over all 392 keys, chunks of 8
    for (int jc = 0; jc < S; jc += 8) {
        float s0[8], s1[8];
        float cm0 = -INFINITY, cm1 = -INFINITY;
#pragma unroll
        for (int u = 0; u < 8; ++u) {
            const float4* kj = &Ks4[(jc + u) * 8];
            float a0 = 0.f, a1 = 0.f, a2 = 0.f, a3 = 0.f;
            float b0 = 0.f, b1 = 0.f, b2 = 0.f, b3 = 0.f;
#pragma unroll
            for (int c = 0; c < 8; ++c) {
                const float4 kk = kj[c];
                a0 = fmaf(q0[4*c+0], kk.x, a0);
                a1 = fmaf(q0[4*c+1], kk.y, a1);
                a2 = fmaf(q0[4*c+2], kk.z, a2);
                a3 = fmaf(q0[4*c+3], kk.w, a3);
                b0 = fmaf(q1[4*c+0], kk.x, b0);
                b1 = fmaf(q1[4*c+1], kk.y, b1);
                b2 = fmaf(q1[4*c+2], kk.z, b2);
                b3 = fmaf(q1[4*c+3], kk.w, b3);
            }
            s0[u] = (a0 + a1) + (a2 + a3);
            s1[u] = (b0 + b1) + (b2 + b3);
            cm0 = fmaxf(cm0, s0[u]);
            cm1 = fmaxf(cm1, s1[u]);
        }
        // deferred rescale (chunk granularity)
        if (cm0 > m0) {
            const float corr = __expf(m0 - cm0);
            l0 *= corr;
#pragma unroll
            for (int d = 0; d < HD; ++d) o0[d] *= corr;
            m0 = cm0;
        }
        if (cm1 > m1) {
            const float corr = __expf(m1 - cm1);
            l1 *= corr;
#pragma unroll
            for (int d = 0; d < HD; ++d) o1[d] *= corr;
            m1 = cm1;
        }
#pragma unroll
        for (int u = 0; u < 8; ++u) {
            const float p0 = __expf(s0[u] - m0);
            const float p1 = __expf(s1[u] - m1);
            l0 += p0;
            l1 += p1;
            const float4* vj = &Vs4[(jc + u) * 8];
#pragma unroll
            for (int c = 0; c < 8; ++c) {
                const float4 vv = vj[c];
                o0[4*c+0] = fmaf(p0, vv.x, o0[4*c+0]);
                o0[4*c+1] = fmaf(p0, vv.y, o0[4*c+1]);
                o0[4*c+2] = fmaf(p0, vv.z, o0[4*c+2]);
                o0[4*c+3] = fmaf(p0, vv.w, o0[4*c+3]);
                o1[4*c+0] = fmaf(p1, vv.x, o1[4*c+0]);
                o1[4*c+1] = fmaf(p1, vv.y, o1[4*c+1]);
                o1[4*c+2] = fmaf(p1, vv.z, o1[4*c+2]);
                o1[4*c+3] = fmaf(p1, vv.w, o1[4*c+3]);
            }
        }
    }

    // ---- LePE: depthwise 3x3 SAME conv on V (window-local zero padding),
    //      written into the dead K buffer with 16B-block XOR swizzle.
    __syncthreads();
    if (tid < 224) {
        const int d  = tid & 31;     // channel within head
        const int xl = tid >> 5;     // window-local column 0..6
        const int c  = coff + d;
        float wv[9];
#pragma unroll
        for (int k = 0; k < 9; ++k) wv[k] = conv_w[c * 9 + k];
        const float bias = conv_b[c];
        for (int y = 0; y < HH; ++y) {
            float acc = bias;
#pragma unroll
            for (int dy = -1; dy <= 1; ++dy) {
#pragma unroll
                for (int dx = -1; dx <= 1; ++dx) {
                    const int yy = y + dy, xx = xl + dx;
                    const bool ok = (yy >= 0) && (yy < HH) && (xx >= 0) && (xx < WSP);
                    const int yc = min(max(yy, 0), HH - 1);
                    const int xc = min(max(xx, 0), WSP - 1);
                    float vv = Vs[(yc * WSP + xc) * HD + d];
                    vv = ok ? vv : 0.f;
                    acc = fmaf(wv[(dy + 1) * 3 + (dx + 1)], vv, acc);
                }
            }
            const int t = y * WSP + xl;
            Ks[t * HD + (((d >> 2) ^ (t & 7)) << 2) + (d & 3)] = acc;
        }
    }
    __syncthreads();

    // ---- epilogue: out = o / l + lepe
    {
        const float inv0 = 1.0f / l0;
        const int n0 = (r0 / WSP) * WW + wi * WSP + (r0 % WSP);
        float4* po = (float4*)(out + ((size_t)b * NTOK + n0) * DIMC + coff);
#pragma unroll
        for (int blk = 0; blk < 8; ++blk) {
            const float4 lp = Ks4[r0 * 8 + (blk ^ (r0 & 7))];
            float4 vo;
            vo.x = o0[4*blk+0] * inv0 + lp.x;
            vo.y = o0[4*blk+1] * inv0 + lp.y;
            vo.z = o0[4*blk+2] * inv0 + lp.z;
            vo.w = o0[4*blk+3] * inv0 + lp.w;
            po[blk] = vo;
        }
        if (w1) {
            const float inv1 = 1.0f / l1;
            const int n1 = (r1 / WSP) * WW + wi * WSP + (r1 % WSP);
            float4* p1 = (float4*)(out + ((size_t)b * NTOK + n1) * DIMC + coff);
#pragma unroll
            for (int blk = 0; blk < 8; ++blk) {
                const float4 lp = Ks4[r1 * 8 + (blk ^ (r1 & 7))];
                float4 vo;
                vo.x = o1[4*blk+0] * inv1 + lp.x;
                vo.y = o1[4*blk+1] * inv1 + lp.y;
                vo.z = o1[4*blk+2] * inv1 + lp.z;
                vo.w = o1[4*blk+3] * inv1 + lp.w;
                p1[blk] = vo;
            }
        }
    }
}

extern "C" void kernel_launch(void* const* d_in, const int* in_sizes, int n_in,
                              void* d_out, int out_size, void* d_ws, size_t ws_size,
                              hipStream_t stream)
{
    const float* qkv    = (const float*)d_in[0];
    const float* conv_w = (const float*)d_in[1];
    const float* conv_b = (const float*)d_in[2];
    // d_in[3], d_in[4] are h, w scalars — fixed at 56 by setup_inputs.
    float* out = (float*)d_out;

    dim3 grid(BATCH * NWIN * NHEAD);   // 1024 blocks: (window, head)
    dim3 block(256);
    lepe_attn_kernel<<<grid, block, 0, stream>>>(qkv, conv_w, conv_b, out);
}

// Round 6
// 593.434 us; speedup vs baseline: 1.6901x; 1.6901x over previous
//
#include <hip/hip_runtime.h>
#include <math.h>

// LePE attention (CSWin vertical split) — bf16 hi/lo split MFMA version.
// b=16, h=w=56, dim=256, heads=8, hd=32 -> 128 windows x 392 tokens, 1024 blocks.
//
// Per block (window,head): K,V staged to LDS as bf16 hi+lo (V transposed),
// 4 waves x q-tiles of 16. QK^T swapped (D[key][q]) via mfma_f32_16x16x32_bf16,
// 3-term split (hh, h*lo, lo*h) ~ fp32 accuracy. Online softmax per-lane
// (lane owns one q col), P repacked through a 1.25KB/wave LDS buffer into the
// PV B-fragment; PV also 3-term split. LePE depthwise 3x3 from Vt(hi+lo) into
// a bf16 LDS buffer, added in the epilogue.

#define BATCH 16
#define HH 56
#define WW 56
#define WSP 7
#define NHEAD 8
#define HD 32
#define DIMC 256
#define NTOK 3136
#define S 392
#define SPAD 416          // keys padded to 13 chunks of 32
#define NCH 13
#define QT 25             // q tiles of 16 (covers 400)
#define QSCALE 0.17677669529663687f

typedef __attribute__((ext_vector_type(8))) short short8;
typedef __attribute__((ext_vector_type(4))) float f32x4;

#define MFMA(A, B, C) __builtin_amdgcn_mfma_f32_16x16x32_bf16((A), (B), (C), 0, 0, 0)

__device__ inline ushort bf16_rne(float f) {
    uint u = __float_as_uint(f);
    return (ushort)((u + 0x7FFFu + ((u >> 16) & 1u)) >> 16);
}
__device__ inline float bf16_f32(ushort h) { return __uint_as_float(((uint)h) << 16); }

__global__ __launch_bounds__(256, 1)
void lepe_attn_mfma(const float* __restrict__ qkv,
                    const float* __restrict__ conv_w,
                    const float* __restrict__ conv_b,
                    float* __restrict__ out)
{
    __shared__ ushort Kh_s[SPAD * HD];     // [key][dim] bf16 hi   26624 B
    __shared__ ushort Kl_s[SPAD * HD];     // [key][dim] bf16 lo   26624 B
    __shared__ ushort Vh_s[HD * SPAD];     // [dim][key] bf16 hi   26624 B
    __shared__ ushort Vl_s[HD * SPAD];     // [dim][key] bf16 lo   26624 B
    __shared__ ushort lepe_s[S * HD];      // [token][dim] bf16    25088 B
    __shared__ ushort P_s[4][2][16 * 40];  // [wave][hi/lo][q][40] 10240 B

    const int tid  = threadIdx.x;
    const int lane = tid & 63;
    const int wv   = tid >> 6;
    const int ql   = lane & 15;    // q column / A-frag row
    const int g    = lane >> 4;    // k-group
    const int bid  = blockIdx.x;
    const int head = bid & 7;
    const int gw   = bid >> 3;
    const int b    = gw >> 3;
    const int wi   = gw & 7;
    const int coff = head * HD;

    const float* qbase = qkv + (size_t)b * NTOK * DIMC;
    const float* kbase = qkv + (size_t)(BATCH + b) * NTOK * DIMC;
    const float* vbase = qkv + (size_t)(2 * BATCH + b) * NTOK * DIMC;

    // ---- zero V pads (keys 392..415) so P=0 x Vpad can never make NaN
    for (int j = tid; j < 24 * HD; j += 256) {
        const int key = S + (j % 24);
        const int d   = j / 24;
        Vh_s[d * SPAD + key] = 0;
        Vl_s[d * SPAD + key] = 0;
    }

    // ---- stage K (row-major) and V (transposed), fp32 -> bf16 hi/lo
    for (int i = tid; i < S * 8; i += 256) {
        const int t  = i >> 3;
        const int f4 = i & 7;
        const int y  = t / WSP, x = t - y * WSP;
        const int n  = y * WW + wi * WSP + x;
        const float4 kk = *(const float4*)(kbase + (size_t)n * DIMC + coff + f4 * 4);
        const float4 vv = *(const float4*)(vbase + (size_t)n * DIMC + coff + f4 * 4);
        ushort h[4], l[4];
#pragma unroll
        for (int j = 0; j < 4; ++j) {
            const float kf = ((const float*)&kk)[j];
            h[j] = bf16_rne(kf);
            l[j] = bf16_rne(kf - bf16_f32(h[j]));
        }
        uint2 wh, wl;
        wh.x = (uint)h[0] | ((uint)h[1] << 16); wh.y = (uint)h[2] | ((uint)h[3] << 16);
        wl.x = (uint)l[0] | ((uint)l[1] << 16); wl.y = (uint)l[2] | ((uint)l[3] << 16);
        *(uint2*)&Kh_s[t * HD + f4 * 4] = wh;
        *(uint2*)&Kl_s[t * HD + f4 * 4] = wl;
#pragma unroll
        for (int j = 0; j < 4; ++j) {
            const float vf = ((const float*)&vv)[j];
            const ushort vh = bf16_rne(vf);
            Vh_s[(f4 * 4 + j) * SPAD + t] = vh;
            Vl_s[(f4 * 4 + j) * SPAD + t] = bf16_rne(vf - bf16_f32(vh));
        }
    }
    __syncthreads();

    // ---- LePE: depthwise 3x3 SAME (window-local), V = hi+lo (exact)
    if (tid < 224) {
        const int d  = tid & 31;
        const int xl = tid >> 5;
        float wvv[9];
#pragma unroll
        for (int k = 0; k < 9; ++k) wvv[k] = conv_w[(coff + d) * 9 + k];
        const float bias = conv_b[coff + d];
        const ushort* vh = &Vh_s[d * SPAD];
        const ushort* vl = &Vl_s[d * SPAD];
        for (int y = 0; y < HH; ++y) {
            float acc = bias;
#pragma unroll
            for (int dy = -1; dy <= 1; ++dy) {
                const int yy = y + dy;
                if (yy < 0 || yy >= HH) continue;
#pragma unroll
                for (int dx = -1; dx <= 1; ++dx) {
                    const int xx = xl + dx;
                    if (xx < 0 || xx >= WSP) continue;
                    const int key = yy * WSP + xx;
                    acc = fmaf(wvv[(dy + 1) * 3 + (dx + 1)],
                               bf16_f32(vh[key]) + bf16_f32(vl[key]), acc);
                }
            }
            lepe_s[(y * WSP + xl) * HD + d] = bf16_rne(acc);
        }
    }
    __syncthreads();

    // ---- main flash loop: wave wv handles q-tiles {wv, wv+4, ...}
    ushort* Ph = &P_s[wv][0][0];
    ushort* Pl = &P_s[wv][1][0];

    for (int qt = wv; qt < QT; qt += 4) {
        const int qtok = qt * 16 + ql;
        const int qc   = (qtok < S) ? qtok : (S - 1);
        const int qy   = qc / WSP, qx = qc - qy * WSP;
        const float* qp = qbase + (size_t)(qy * WW + wi * WSP + qx) * DIMC + coff + g * 8;
        short8 Qh, Qlo;
#pragma unroll
        for (int j = 0; j < 8; ++j) {
            const float q = qp[j] * QSCALE;
            const ushort hh = bf16_rne(q);
            Qh[j]  = (short)hh;
            Qlo[j] = (short)bf16_rne(q - bf16_f32(hh));
        }
        f32x4 O0 = {0.f, 0.f, 0.f, 0.f};
        f32x4 O1 = {0.f, 0.f, 0.f, 0.f};
        float m = -INFINITY, lsum = 0.f;

        for (int c = 0; c < NCH; ++c) {
            // K fragments (tiles 2c, 2c+1): A row = ql, dims 8g..8g+7
            const short8 KaH = *(const short8*)&Kh_s[(c * 32 + ql) * HD + g * 8];
            const short8 KaL = *(const short8*)&Kl_s[(c * 32 + ql) * HD + g * 8];
            const short8 KbH = *(const short8*)&Kh_s[(c * 32 + 16 + ql) * HD + g * 8];
            const short8 KbL = *(const short8*)&Kl_s[(c * 32 + 16 + ql) * HD + g * 8];
            f32x4 sa = {0.f, 0.f, 0.f, 0.f};
            f32x4 sb = {0.f, 0.f, 0.f, 0.f};
            sa = MFMA(KaH, Qh, sa); sa = MFMA(KaH, Qlo, sa); sa = MFMA(KaL, Qh, sa);
            sb = MFMA(KbH, Qh, sb); sb = MFMA(KbH, Qlo, sb); sb = MFMA(KbL, Qh, sb);

            if (c == NCH - 1) {   // mask keys >= 392 (D rows: key = c*32 (+16) + 4g + r)
#pragma unroll
                for (int r = 0; r < 4; ++r) {
                    if (c * 32 + 4 * g + r >= S)      sa[r] = -1e30f;
                    if (c * 32 + 16 + 4 * g + r >= S) sb[r] = -1e30f;
                }
            }

            float tmax = fmaxf(fmaxf(fmaxf(sa[0], sa[1]), fmaxf(sa[2], sa[3])),
                               fmaxf(fmaxf(sb[0], sb[1]), fmaxf(sb[2], sb[3])));
            tmax = fmaxf(tmax, __shfl_xor(tmax, 16));
            tmax = fmaxf(tmax, __shfl_xor(tmax, 32));
            const float mnew = fmaxf(m, tmax);
            const float corr = __expf(m - mnew);   // first iter: exp(-inf)=0
            m = mnew;
            lsum *= corr;
#pragma unroll
            for (int r = 0; r < 4; ++r) { O0[r] *= corr; O1[r] *= corr; }

            float pa[4], pb[4];
#pragma unroll
            for (int r = 0; r < 4; ++r) {
                pa[r] = __expf(sa[r] - m);
                pb[r] = __expf(sb[r] - m);
                lsum += pa[r] + pb[r];
            }
            // pack P hi/lo and write: tile-a cols 4g..4g+3, tile-b cols 16+4g..+3
            ushort ah[4], al[4], bh[4], bl[4];
#pragma unroll
            for (int r = 0; r < 4; ++r) {
                ah[r] = bf16_rne(pa[r]); al[r] = bf16_rne(pa[r] - bf16_f32(ah[r]));
                bh[r] = bf16_rne(pb[r]); bl[r] = bf16_rne(pb[r] - bf16_f32(bh[r]));
            }
            uint2 w;
            w.x = (uint)ah[0] | ((uint)ah[1] << 16); w.y = (uint)ah[2] | ((uint)ah[3] << 16);
            *(uint2*)&Ph[ql * 40 + 4 * g] = w;
            w.x = (uint)bh[0] | ((uint)bh[1] << 16); w.y = (uint)bh[2] | ((uint)bh[3] << 16);
            *(uint2*)&Ph[ql * 40 + 16 + 4 * g] = w;
            w.x = (uint)al[0] | ((uint)al[1] << 16); w.y = (uint)al[2] | ((uint)al[3] << 16);
            *(uint2*)&Pl[ql * 40 + 4 * g] = w;
            w.x = (uint)bl[0] | ((uint)bl[1] << 16); w.y = (uint)bl[2] | ((uint)bl[3] << 16);
            *(uint2*)&Pl[ql * 40 + 16 + 4 * g] = w;

            // read back P as B-fragment (keys 8g..8g+7 for col ql)
            const short8 PfH = *(const short8*)&Ph[ql * 40 + 8 * g];
            const short8 PfL = *(const short8*)&Pl[ql * 40 + 8 * g];
            // V^T fragments: A row = dim (dt*16 + ql), keys c*32 + 8g..+7
            const short8 V0H = *(const short8*)&Vh_s[ql * SPAD + c * 32 + 8 * g];
            const short8 V0L = *(const short8*)&Vl_s[ql * SPAD + c * 32 + 8 * g];
            const short8 V1H = *(const short8*)&Vh_s[(16 + ql) * SPAD + c * 32 + 8 * g];
            const short8 V1L = *(const short8*)&Vl_s[(16 + ql) * SPAD + c * 32 + 8 * g];
            O0 = MFMA(V0H, PfH, O0); O0 = MFMA(V0L, PfH, O0); O0 = MFMA(V0H, PfL, O0);
            O1 = MFMA(V1H, PfH, O1); O1 = MFMA(V1L, PfH, O1); O1 = MFMA(V1H, PfL, O1);
        }

        lsum += __shfl_xor(lsum, 16);
        lsum += __shfl_xor(lsum, 32);
        const float inv = 1.f / lsum;

        if (qtok < S) {
            const int oy = qtok / WSP, ox = qtok - oy * WSP;
            float* op = out + ((size_t)b * NTOK + oy * WW + wi * WSP + ox) * DIMC + coff;
            float4 o0v, o1v;
            o0v.x = O0[0] * inv + bf16_f32(lepe_s[qtok * HD + 4 * g + 0]);
            o0v.y = O0[1] * inv + bf16_f32(lepe_s[qtok * HD + 4 * g + 1]);
            o0v.z = O0[2] * inv + bf16_f32(lepe_s[qtok * HD + 4 * g + 2]);
            o0v.w = O0[3] * inv + bf16_f32(lepe_s[qtok * HD + 4 * g + 3]);
            o1v.x = O1[0] * inv + bf16_f32(lepe_s[qtok * HD + 16 + 4 * g + 0]);
            o1v.y = O1[1] * inv + bf16_f32(lepe_s[qtok * HD + 16 + 4 * g + 1]);
            o1v.z = O1[2] * inv + bf16_f32(lepe_s[qtok * HD + 16 + 4 * g + 2]);
            o1v.w = O1[3] * inv + bf16_f32(lepe_s[qtok * HD + 16 + 4 * g + 3]);
            *(float4*)(op + 4 * g)      = o0v;
            *(float4*)(op + 16 + 4 * g) = o1v;
        }
    }
}

extern "C" void kernel_launch(void* const* d_in, const int* in_sizes, int n_in,
                              void* d_out, int out_size, void* d_ws, size_t ws_size,
                              hipStream_t stream)
{
    const float* qkv    = (const float*)d_in[0];
    const float* conv_w = (const float*)d_in[1];
    const float* conv_b = (const float*)d_in[2];
    float* out = (float*)d_out;

    dim3 grid(BATCH * 8 * NHEAD);   // 1024 blocks: (window, head)
    dim3 block(256);
    lepe_attn_mfma<<<grid, block, 0, stream>>>(qkv, conv_w, conv_b, out);
}

// Round 7
// 403.846 us; speedup vs baseline: 2.4835x; 1.4695x over previous
//
#include <hip/hip_runtime.h>
#include <math.h>

// LePE attention (CSWin vertical split) — bf16 hi/lo split MFMA, v2.
// Round-6 post-mortem: 443 µs, SQ_LDS_BANK_CONFLICT=1.2e8 (8-way on K/V
// fragment reads), occupancy 1 wave/SIMD. v2: (a) XOR slot-swizzle on K and
// V^T LDS layouts (read-side swizzle term is the per-lane constant
// (ql>>1)&3 -> zero loop overhead, 8-way -> 2-way=free); (b) 512 threads /
// 8 waves (2/SIMD) for latency overlap; (c) lepe buffer 8B-granule swizzle +
// uint2 epilogue reads.

#define BATCH 16
#define HH 56
#define WW 56
#define WSP 7
#define NHEAD 8
#define HD 32
#define DIMC 256
#define NTOK 3136
#define S 392
#define SPAD 416          // keys padded to 13 chunks of 32
#define NCH 13
#define QT 25             // q tiles of 16 (covers 400)
#define QSCALE 0.17677669529663687f

typedef __attribute__((ext_vector_type(8))) short short8;
typedef __attribute__((ext_vector_type(4))) float f32x4;

#define MFMA(A, B, C) __builtin_amdgcn_mfma_f32_16x16x32_bf16((A), (B), (C), 0, 0, 0)

__device__ inline ushort bf16_rne(float f) {
    uint u = __float_as_uint(f);
    return (ushort)((u + 0x7FFFu + ((u >> 16) & 1u)) >> 16);
}
__device__ inline float bf16_f32(ushort h) { return __uint_as_float(((uint)h) << 16); }

__global__ __launch_bounds__(512, 1)
void lepe_attn_mfma(const float* __restrict__ qkv,
                    const float* __restrict__ conv_w,
                    const float* __restrict__ conv_b,
                    float* __restrict__ out)
{
    // K rows (32 ushort): 4 slots of 16B, slot' = slot ^ ((t>>1)&3)
    // V rows (SPAD ushort): per 32-key chunk, 16B granule s' = s ^ ((d>>1)&3)
    // lepe rows (32 ushort): 8B granule gr' = gr ^ (t&7)
    __shared__ ushort Kh_s[SPAD * HD];     // [key][dim] hi     26624 B
    __shared__ ushort Kl_s[SPAD * HD];     // [key][dim] lo     26624 B
    __shared__ ushort Vh_s[HD * SPAD];     // [dim][key] hi     26624 B
    __shared__ ushort Vl_s[HD * SPAD];     // [dim][key] lo     26624 B
    __shared__ ushort lepe_s[S * HD];      //                   25088 B
    __shared__ ushort P_s[8][2][16 * 40];  // per-wave P buf    20480 B

    const int tid  = threadIdx.x;
    const int lane = tid & 63;
    const int wv   = tid >> 6;
    const int ql   = lane & 15;          // q column / A-frag row
    const int g    = lane >> 4;          // k/dim sub-group
    const int slot = ((g ^ ((ql >> 1) & 3)) << 3);  // swizzled 16B-slot (ushorts)
    const int bid  = blockIdx.x;
    const int head = bid & 7;
    const int gw   = bid >> 3;
    const int b    = gw >> 3;
    const int wi   = gw & 7;
    const int coff = head * HD;

    const float* qbase = qkv + (size_t)b * NTOK * DIMC;
    const float* kbase = qkv + (size_t)(BATCH + b) * NTOK * DIMC;
    const float* vbase = qkv + (size_t)(2 * BATCH + b) * NTOK * DIMC;

    // ---- zero V pad chunk (physical keys 384..415; real 384..391 overwritten)
    for (int j = tid; j < 32 * HD; j += 512) {
        const int d = j >> 5, o = j & 31;
        Vh_s[d * SPAD + 384 + o] = 0;
        Vl_s[d * SPAD + 384 + o] = 0;
    }

    // ---- stage K (row-major, slot-swizzled) and V (transposed, swizzled)
    for (int i = tid; i < S * 8; i += 512) {
        const int t  = i >> 3;
        const int f4 = i & 7;
        const int y  = t / WSP, x = t - y * WSP;
        const int n  = y * WW + wi * WSP + x;
        const float4 kk = *(const float4*)(kbase + (size_t)n * DIMC + coff + f4 * 4);
        const float4 vv = *(const float4*)(vbase + (size_t)n * DIMC + coff + f4 * 4);
        ushort h[4], l[4];
#pragma unroll
        for (int j = 0; j < 4; ++j) {
            const float kf = ((const float*)&kk)[j];
            h[j] = bf16_rne(kf);
            l[j] = bf16_rne(kf - bf16_f32(h[j]));
        }
        uint2 wh, wl;
        wh.x = (uint)h[0] | ((uint)h[1] << 16); wh.y = (uint)h[2] | ((uint)h[3] << 16);
        wl.x = (uint)l[0] | ((uint)l[1] << 16); wl.y = (uint)l[2] | ((uint)l[3] << 16);
        const int kidx = t * HD + ((f4 << 2) ^ (((t >> 1) & 3) << 3));
        *(uint2*)&Kh_s[kidx] = wh;
        *(uint2*)&Kl_s[kidx] = wl;
#pragma unroll
        for (int j = 0; j < 4; ++j) {
            const int d = f4 * 4 + j;
            const float vf = ((const float*)&vv)[j];
            const ushort vh = bf16_rne(vf);
            const int vidx = d * SPAD + (t ^ (((d >> 1) & 3) << 3));
            Vh_s[vidx] = vh;
            Vl_s[vidx] = bf16_rne(vf - bf16_f32(vh));
        }
    }
    __syncthreads();

    // ---- LePE: depthwise 3x3 SAME (window-local), V = hi+lo (exact), 448 thr
    if (tid < 448) {
        const int d  = tid & 31;
        const int q  = tid >> 5;        // 0..13
        const int xl = q % 7;
        const int y0 = (q / 7) * 28;    // 0 or 28
        const int dsw = ((d >> 1) & 3) << 3;
        float wvv[9];
#pragma unroll
        for (int k = 0; k < 9; ++k) wvv[k] = conv_w[(coff + d) * 9 + k];
        const float bias = conv_b[coff + d];
        const ushort* vh = &Vh_s[d * SPAD];
        const ushort* vl = &Vl_s[d * SPAD];
        for (int y = y0; y < y0 + 28; ++y) {
            float acc = bias;
#pragma unroll
            for (int dy = -1; dy <= 1; ++dy) {
                const int yy = y + dy;
                if (yy < 0 || yy >= HH) continue;
#pragma unroll
                for (int dx = -1; dx <= 1; ++dx) {
                    const int xx = xl + dx;
                    if (xx < 0 || xx >= WSP) continue;
                    const int key = (yy * WSP + xx) ^ dsw;   // swizzled V index
                    acc = fmaf(wvv[(dy + 1) * 3 + (dx + 1)],
                               bf16_f32(vh[key]) + bf16_f32(vl[key]), acc);
                }
            }
            const int t = y * WSP + xl;
            lepe_s[t * HD + (d ^ ((t & 7) << 2))] = bf16_rne(acc);
        }
    }
    __syncthreads();

    // ---- main flash loop: wave wv handles q-tiles {wv, wv+8, ...}
    ushort* Ph = &P_s[wv][0][0];
    ushort* Pl = &P_s[wv][1][0];

    for (int qt = wv; qt < QT; qt += 8) {
        const int qtok = qt * 16 + ql;
        const int qc   = (qtok < S) ? qtok : (S - 1);
        const int qy   = qc / WSP, qx = qc - qy * WSP;
        const float* qp = qbase + (size_t)(qy * WW + wi * WSP + qx) * DIMC + coff + g * 8;
        short8 Qh, Qlo;
#pragma unroll
        for (int j = 0; j < 8; ++j) {
            const float q = qp[j] * QSCALE;
            const ushort hh = bf16_rne(q);
            Qh[j]  = (short)hh;
            Qlo[j] = (short)bf16_rne(q - bf16_f32(hh));
        }
        f32x4 O0 = {0.f, 0.f, 0.f, 0.f};
        f32x4 O1 = {0.f, 0.f, 0.f, 0.f};
        float m = -INFINITY, lsum = 0.f;

        for (int c = 0; c < NCH; ++c) {
            // K fragments: rows c*32+ql / +16, swizzled slot (per-lane const)
            const short8 KaH = *(const short8*)&Kh_s[(c * 32 + ql) * HD + slot];
            const short8 KaL = *(const short8*)&Kl_s[(c * 32 + ql) * HD + slot];
            const short8 KbH = *(const short8*)&Kh_s[(c * 32 + 16 + ql) * HD + slot];
            const short8 KbL = *(const short8*)&Kl_s[(c * 32 + 16 + ql) * HD + slot];
            f32x4 sa = {0.f, 0.f, 0.f, 0.f};
            f32x4 sb = {0.f, 0.f, 0.f, 0.f};
            sa = MFMA(KaH, Qh, sa); sa = MFMA(KaH, Qlo, sa); sa = MFMA(KaL, Qh, sa);
            sb = MFMA(KbH, Qh, sb); sb = MFMA(KbH, Qlo, sb); sb = MFMA(KbL, Qh, sb);

            if (c == NCH - 1) {   // mask keys >= 392
#pragma unroll
                for (int r = 0; r < 4; ++r) {
                    if (c * 32 + 4 * g + r >= S)      sa[r] = -1e30f;
                    if (c * 32 + 16 + 4 * g + r >= S) sb[r] = -1e30f;
                }
            }

            float tmax = fmaxf(fmaxf(fmaxf(sa[0], sa[1]), fmaxf(sa[2], sa[3])),
                               fmaxf(fmaxf(sb[0], sb[1]), fmaxf(sb[2], sb[3])));
            tmax = fmaxf(tmax, __shfl_xor(tmax, 16));
            tmax = fmaxf(tmax, __shfl_xor(tmax, 32));
            const float mnew = fmaxf(m, tmax);
            const float corr = __expf(m - mnew);   // first iter: exp(-inf)=0
            m = mnew;
            lsum *= corr;
#pragma unroll
            for (int r = 0; r < 4; ++r) { O0[r] *= corr; O1[r] *= corr; }

            float pa[4], pb[4];
#pragma unroll
            for (int r = 0; r < 4; ++r) {
                pa[r] = __expf(sa[r] - m);
                pb[r] = __expf(sb[r] - m);
                lsum += pa[r] + pb[r];
            }
            ushort ah[4], al[4], bh[4], bl[4];
#pragma unroll
            for (int r = 0; r < 4; ++r) {
                ah[r] = bf16_rne(pa[r]); al[r] = bf16_rne(pa[r] - bf16_f32(ah[r]));
                bh[r] = bf16_rne(pb[r]); bl[r] = bf16_rne(pb[r] - bf16_f32(bh[r]));
            }
            uint2 w;
            w.x = (uint)ah[0] | ((uint)ah[1] << 16); w.y = (uint)ah[2] | ((uint)ah[3] << 16);
            *(uint2*)&Ph[ql * 40 + 4 * g] = w;
            w.x = (uint)bh[0] | ((uint)bh[1] << 16); w.y = (uint)bh[2] | ((uint)bh[3] << 16);
            *(uint2*)&Ph[ql * 40 + 16 + 4 * g] = w;
            w.x = (uint)al[0] | ((uint)al[1] << 16); w.y = (uint)al[2] | ((uint)al[3] << 16);
            *(uint2*)&Pl[ql * 40 + 4 * g] = w;
            w.x = (uint)bl[0] | ((uint)bl[1] << 16); w.y = (uint)bl[2] | ((uint)bl[3] << 16);
            *(uint2*)&Pl[ql * 40 + 16 + 4 * g] = w;

            const short8 PfH = *(const short8*)&Ph[ql * 40 + 8 * g];
            const short8 PfL = *(const short8*)&Pl[ql * 40 + 8 * g];
            // V^T fragments: rows ql / 16+ql, chunk c, swizzled slot
            const short8 V0H = *(const short8*)&Vh_s[ql * SPAD + c * 32 + slot];
            const short8 V0L = *(const short8*)&Vl_s[ql * SPAD + c * 32 + slot];
            const short8 V1H = *(const short8*)&Vh_s[(16 + ql) * SPAD + c * 32 + slot];
            const short8 V1L = *(const short8*)&Vl_s[(16 + ql) * SPAD + c * 32 + slot];
            O0 = MFMA(V0H, PfH, O0); O0 = MFMA(V0L, PfH, O0); O0 = MFMA(V0H, PfL, O0);
            O1 = MFMA(V1H, PfH, O1); O1 = MFMA(V1L, PfH, O1); O1 = MFMA(V1H, PfL, O1);
        }

        lsum += __shfl_xor(lsum, 16);
        lsum += __shfl_xor(lsum, 32);
        const float inv = 1.f / lsum;

        if (qtok < S) {
            const int oy = qtok / WSP, ox = qtok - oy * WSP;
            float* op = out + ((size_t)b * NTOK + oy * WW + wi * WSP + ox) * DIMC + coff;
            const uint2 w0 = *(const uint2*)&lepe_s[qtok * HD + ((g ^ (qtok & 7)) << 2)];
            const uint2 w1 = *(const uint2*)&lepe_s[qtok * HD + (((g + 4) ^ (qtok & 7)) << 2)];
            float4 o0v, o1v;
            o0v.x = O0[0] * inv + bf16_f32((ushort)(w0.x & 0xffff));
            o0v.y = O0[1] * inv + bf16_f32((ushort)(w0.x >> 16));
            o0v.z = O0[2] * inv + bf16_f32((ushort)(w0.y & 0xffff));
            o0v.w = O0[3] * inv + bf16_f32((ushort)(w0.y >> 16));
            o1v.x = O1[0] * inv + bf16_f32((ushort)(w1.x & 0xffff));
            o1v.y = O1[1] * inv + bf16_f32((ushort)(w1.x >> 16));
            o1v.z = O1[2] * inv + bf16_f32((ushort)(w1.y & 0xffff));
            o1v.w = O1[3] * inv + bf16_f32((ushort)(w1.y >> 16));
            *(float4*)(op + 4 * g)      = o0v;
            *(float4*)(op + 16 + 4 * g) = o1v;
        }
    }
}

extern "C" void kernel_launch(void* const* d_in, const int* in_sizes, int n_in,
                              void* d_out, int out_size, void* d_ws, size_t ws_size,
                              hipStream_t stream)
{
    const float* qkv    = (const float*)d_in[0];
    const float* conv_w = (const float*)d_in[1];
    const float* conv_b = (const float*)d_in[2];
    float* out = (float*)d_out;

    dim3 grid(BATCH * 8 * NHEAD);   // 1024 blocks: (window, head)
    dim3 block(512);                // 8 waves, 2 per SIMD
    lepe_attn_mfma<<<grid, block, 0, stream>>>(qkv, conv_w, conv_b, out);
}